// Round 7
// baseline (442.913 us; speedup 1.0000x reference)
//
#include <hip/hip_runtime.h>

// ChebClassifier R16: R15 base + fp16-only Chebyshev state at levels 0+1.
// - Level 0: Ah0 [N0][32] fp16 IS the state (slots k=0..5); fp32 Tb slabs
//   deleted; prop0 gathers 8B/edge (was 16B), prev read fp16.
// - Level 1: Th1 fp16 slabs are the only state; fp32 Tlvl1 deleted.
//   Each step: write 6.4MB (was 19.2), prev read 6.4MB fp16 (was 12.8 fp32).
// - pool0 writes fp16 only (was fp32+fp16).
// - Level 2 keeps fp32 recurrence state (error containment, tiny traffic).
// Build = R15 two-phase radix CSR. ~140MB less traffic total.

namespace {
constexpr int cN0 = 100000, cN1 = 25000, cN2 = 6250;
constexpr int cE0 = 600000, cE1 = 150000, cE2 = 37500;
constexpr int cD  = cN2 * 256;

// jobs 0-4: dst-keyed CSR builds (conv0, conv1, conv2, pool0, pool1)
constexpr int JN[5]  = {cN0, cN1, cN2, cN1, cN2};
constexpr int JE[5]  = {cE0, cE1, cE2, 100000, 25000};
constexpr int JB[5]  = {391, 98, 25, 98, 25};
constexpr int JBBASE[6] = {0, 391, 489, 514, 612, 637};
constexpr int TB = 637;
constexpr int JCB[5] = {293, 74, 19, 49, 13};
constexpr int JCBASE[6] = {0, 293, 367, 386, 435, 448};
constexpr int TCB = 448;
constexpr int CHUNK = 2048;
constexpr int BSTRIDE = 400;

constexpr int EBASE[5]   = {0, 600000, 750000, 787500, 887500};
constexpr int E_TOTAL    = 912500;
constexpr int NBASE[5]   = {0, 100096, 125184, 131584, 156672};
constexpr int NPAD_TOTAL = 163072;
constexpr int DEGBASE[3] = {0, 100000, 125000};
constexpr int DEG_TOTAL  = 131250;
constexpr int WPREP_TOTAL = 768 * 128 + 768 * 256 + 128 * 32;
constexpr int PREP_ALL_TOTAL = WPREP_TOTAL + DEG_TOTAL + cN0 + 10;
}

typedef __attribute__((ext_vector_type(8))) short short8;
typedef __attribute__((ext_vector_type(4))) float floatx4;

__device__ inline ushort f2h(float f) {
  union { _Float16 h; ushort u; } v;
  v.h = (_Float16)f;
  return v.u;
}
__device__ inline float h2f(unsigned lo16) {
  union { ushort u; _Float16 h; } v;
  v.u = (ushort)lo16;
  return (float)v.h;
}

__device__ inline int job_of_cb(int cb) {
  int j = 0;
  while (cb >= JCBASE[j + 1]) ++j;
  return j;
}
__device__ inline int job_of_bucket(int g) {
  int j = 0;
  while (g >= JBBASE[j + 1]) ++j;
  return j;
}

// ---------------- two-phase radix CSR build (R12/R15) ----------------
__global__ __launch_bounds__(256) void c1_count_kernel(
    const int* __restrict__ k0, const int* __restrict__ k1, const int* __restrict__ k2,
    const int* __restrict__ k3, const int* __restrict__ k4,
    const int* __restrict__ s0, const int* __restrict__ s1, const int* __restrict__ s2,
    int* __restrict__ degcnt, int* __restrict__ cntCB) {
  __shared__ int cnt[BSTRIDE];
  int cb = blockIdx.x;
  int j = job_of_cb(cb);
  int lb = cb - JCBASE[j];
  const int* keys;
  const int* srck = nullptr;
  int dbase = 0;
  switch (j) {
    case 0: keys = k0; srck = s0; dbase = DEGBASE[0]; break;
    case 1: keys = k1; srck = s1; dbase = DEGBASE[1]; break;
    case 2: keys = k2; srck = s2; dbase = DEGBASE[2]; break;
    case 3: keys = k3; break;
    default: keys = k4; break;
  }
  int nB = JB[j];
  for (int b = threadIdx.x; b < nB; b += 256) cnt[b] = 0;
  __syncthreads();
  int e0 = lb * CHUNK;
  int e1 = min(e0 + CHUNK, JE[j]);
  for (int e = e0 + threadIdx.x; e < e1; e += 256) {
    atomicAdd(&cnt[keys[e] >> 8], 1);
    if (srck) atomicAdd(&degcnt[dbase + srck[e]], 1);
  }
  __syncthreads();
  for (int b = threadIdx.x; b < nB; b += 256)
    cntCB[cb * BSTRIDE + b] = cnt[b];
}

__global__ __launch_bounds__(256) void c2a_scan_kernel(int* __restrict__ cntCB,
                                                       int* __restrict__ bucketTot,
                                                       const int* __restrict__ degcnt,
                                                       float* __restrict__ dinv) {
  __shared__ int s[256];
  int g = blockIdx.x;
  int j = job_of_bucket(g);
  int b = g - JBBASE[j];
  int cb0 = JCBASE[j], nCB = JCB[j];
  int carry = 0;
  for (int c0 = 0; c0 < nCB; c0 += 256) {
    int i = c0 + threadIdx.x;
    int v = (i < nCB) ? cntCB[(cb0 + i) * BSTRIDE + b] : 0;
    s[threadIdx.x] = v;
    __syncthreads();
    for (int d = 1; d < 256; d <<= 1) {
      int t = (threadIdx.x >= d) ? s[threadIdx.x - d] : 0;
      __syncthreads();
      s[threadIdx.x] += t;
      __syncthreads();
    }
    if (i < nCB) cntCB[(cb0 + i) * BSTRIDE + b] = carry + s[threadIdx.x] - v;
    carry += s[255];
    __syncthreads();
  }
  if (threadIdx.x == 0) bucketTot[g] = carry;
  int idx = blockIdx.x * 256 + threadIdx.x;
  if (idx < DEG_TOTAL) {
    int c = degcnt[idx];
    dinv[idx] = (c > 0) ? rsqrtf((float)c) : 0.f;
  }
}

__global__ __launch_bounds__(256) void c2b_scan_kernel(const int* __restrict__ bucketTot,
                                                       int* __restrict__ bucketBase) {
  __shared__ int s[256];
  int j = blockIdx.x;
  int g0 = JBBASE[j], nB = JB[j];
  int carry = 0;
  for (int c0 = 0; c0 < nB; c0 += 256) {
    int i = c0 + threadIdx.x;
    int v = (i < nB) ? bucketTot[g0 + i] : 0;
    s[threadIdx.x] = v;
    __syncthreads();
    for (int d = 1; d < 256; d <<= 1) {
      int t = (threadIdx.x >= d) ? s[threadIdx.x - d] : 0;
      __syncthreads();
      s[threadIdx.x] += t;
      __syncthreads();
    }
    if (i < nB) bucketBase[g0 + i] = carry + s[threadIdx.x] - v;
    carry += s[255];
    __syncthreads();
  }
}

__global__ __launch_bounds__(256) void c3_dst_kernel(
    const int* __restrict__ d0, const int* __restrict__ s0,
    const int* __restrict__ d1, const int* __restrict__ s1,
    const int* __restrict__ d2, const int* __restrict__ s2,
    const int* __restrict__ p0r, const int* __restrict__ p0c, const float* __restrict__ p0v,
    const int* __restrict__ p1r, const int* __restrict__ p1c, const float* __restrict__ p1v,
    const float* __restrict__ dinv,
    const int* __restrict__ cntCB, const int* __restrict__ bucketBase,
    int2* __restrict__ scatPairs) {
  __shared__ int base[BSTRIDE];
  int cb = blockIdx.x;
  int j = job_of_cb(cb);
  int lb = cb - JCBASE[j];
  const int* dk; const int* sk; const float* vv = nullptr;
  switch (j) {
    case 0: dk = d0; sk = s0; break;
    case 1: dk = d1; sk = s1; break;
    case 2: dk = d2; sk = s2; break;
    case 3: dk = p0r; sk = p0c; vv = p0v; break;
    default: dk = p1r; sk = p1c; vv = p1v; break;
  }
  int nB = JB[j];
  for (int b = threadIdx.x; b < nB; b += 256)
    base[b] = EBASE[j] + bucketBase[JBBASE[j] + b] + cntCB[cb * BSTRIDE + b];
  __syncthreads();
  int e0 = lb * CHUNK;
  int e1 = min(e0 + CHUNK, JE[j]);
  for (int e = e0 + threadIdx.x; e < e1; e += 256) {
    int d = dk[e];
    int s = sk[e];
    float w;
    if (j < 3) w = -(dinv[DEGBASE[j] + s] * dinv[DEGBASE[j] + d]);
    else w = vv[e];
    int pos = atomicAdd(&base[d >> 8], 1);
    scatPairs[pos] = make_int2(((d & 255) << 17) | s, __float_as_int(w));
  }
}

__global__ __launch_bounds__(256) void dcsr_kernel(const int2* __restrict__ scatPairs,
                                                   const int* __restrict__ bucketTot,
                                                   const int* __restrict__ bucketBase,
                                                   int* __restrict__ off,
                                                   int2* __restrict__ csrPairs) {
  __shared__ int cnt[256];
  __shared__ int sArr[256];
  __shared__ int cur[256];
  int g = blockIdx.x;
  int j = job_of_bucket(g);
  int b = g - JBBASE[j];
  int relBase = bucketBase[g];
  int st = EBASE[j] + relBase;
  int en = st + bucketTot[g];
  cnt[threadIdx.x] = 0;
  __syncthreads();
  for (int idx = st + threadIdx.x; idx < en; idx += 256)
    atomicAdd(&cnt[scatPairs[idx].x >> 17], 1);
  __syncthreads();
  int v = cnt[threadIdx.x];
  sArr[threadIdx.x] = v;
  __syncthreads();
  for (int d = 1; d < 256; d <<= 1) {
    int t = (threadIdx.x >= d) ? sArr[threadIdx.x - d] : 0;
    __syncthreads();
    sArr[threadIdx.x] += t;
    __syncthreads();
  }
  int excl = sArr[threadIdx.x] - v;
  int node = b * 256 + threadIdx.x;
  if (node < JN[j]) off[NBASE[j] + node] = relBase + excl;
  if (threadIdx.x == 0 && b == JB[j] - 1) off[NBASE[j] + JN[j]] = JE[j];
  cur[threadIdx.x] = st + excl;
  __syncthreads();
  for (int idx = st + threadIdx.x; idx < en; idx += 256) {
    int2 p = scatPairs[idx];
    int dl = p.x >> 17;
    int s = p.x & 0x1FFFF;
    int pos = atomicAdd(&cur[dl], 1);
    csrPairs[pos] = make_int2(s, p.y);
  }
}

// ---------------- unified prop/pool over 128-wide fp16 rows ----------------
// Gathers fp16 rows hh[.][128]; fp32 accumulate; optional prev as fp32 rows
// (prevF) OR fp16 rows (prevH); optional fp32 output y; always fp16 yh.
__global__ __launch_bounds__(256) void csr_prop128h_kernel(
    const int* __restrict__ off, const int2* __restrict__ pairs,
    const ushort* __restrict__ hh, float* __restrict__ y, ushort* __restrict__ yh,
    const float* __restrict__ prevF, const ushort* __restrict__ prevH,
    float scale, int N) {
  int r = blockIdx.x * 8 + (threadIdx.x >> 5);
  int l = threadIdx.x & 31;
  if (r >= N) return;
  int s = off[r], e = off[r + 1];
  const uint2* h2 = (const uint2*)hh;
  float ax = 0.f, ay = 0.f, az = 0.f, aw = 0.f;
  int j = s;
  for (; j + 4 <= e; j += 4) {
    int2 p0 = pairs[j], p1 = pairs[j + 1], p2 = pairs[j + 2], p3 = pairs[j + 3];
    uint2 v0 = h2[(size_t)p0.x * 32 + l];
    uint2 v1 = h2[(size_t)p1.x * 32 + l];
    uint2 v2 = h2[(size_t)p2.x * 32 + l];
    uint2 v3 = h2[(size_t)p3.x * 32 + l];
    float w0 = __int_as_float(p0.y), w1 = __int_as_float(p1.y);
    float w2 = __int_as_float(p2.y), w3 = __int_as_float(p3.y);
    ax += w0 * h2f(v0.x & 0xFFFFu) + w1 * h2f(v1.x & 0xFFFFu)
        + w2 * h2f(v2.x & 0xFFFFu) + w3 * h2f(v3.x & 0xFFFFu);
    ay += w0 * h2f(v0.x >> 16) + w1 * h2f(v1.x >> 16)
        + w2 * h2f(v2.x >> 16) + w3 * h2f(v3.x >> 16);
    az += w0 * h2f(v0.y & 0xFFFFu) + w1 * h2f(v1.y & 0xFFFFu)
        + w2 * h2f(v2.y & 0xFFFFu) + w3 * h2f(v3.y & 0xFFFFu);
    aw += w0 * h2f(v0.y >> 16) + w1 * h2f(v1.y >> 16)
        + w2 * h2f(v2.y >> 16) + w3 * h2f(v3.y >> 16);
  }
  for (; j < e; ++j) {
    int2 p = pairs[j];
    uint2 v0 = h2[(size_t)p.x * 32 + l];
    float w = __int_as_float(p.y);
    ax += w * h2f(v0.x & 0xFFFFu);
    ay += w * h2f(v0.x >> 16);
    az += w * h2f(v0.y & 0xFFFFu);
    aw += w * h2f(v0.y >> 16);
  }
  float4 v = make_float4(scale * ax, scale * ay, scale * az, scale * aw);
  if (prevF) {
    float4 pv = ((const float4*)prevF)[(size_t)r * 32 + l];
    v.x -= pv.x; v.y -= pv.y; v.z -= pv.z; v.w -= pv.w;
  } else if (prevH) {
    uint2 pv = ((const uint2*)prevH)[(size_t)r * 32 + l];
    v.x -= h2f(pv.x & 0xFFFFu);
    v.y -= h2f(pv.x >> 16);
    v.z -= h2f(pv.y & 0xFFFFu);
    v.w -= h2f(pv.y >> 16);
  }
  if (y) ((float4*)y)[(size_t)r * 32 + l] = v;
  uint2 sp = make_uint2(f2h(v.x) | ((unsigned)f2h(v.y) << 16),
                        f2h(v.z) | ((unsigned)f2h(v.w) << 16));
  ((uint2*)yh)[(size_t)r * 32 + l] = sp;
}

// level-0: fp16-only state in Ah[N0][32] (slot k = halves 4k..4k+3: x,y,z,0).
// 4 lanes/row, quad shuffle reduce; gather 8B/edge from slot kin; prev from
// slot kprev; write slot kout.
__global__ __launch_bounds__(256) void csr_prop0_kernel(
    const int* __restrict__ off, const int2* __restrict__ pairs,
    ushort* __restrict__ Ah, float scale, int N, int kin, int kout, int kprev) {
  int t = blockIdx.x * 256 + threadIdx.x;
  int r = t >> 2;
  int q = t & 3;
  if (r >= N) return;
  int s = off[r], e = off[r + 1];
  float ax = 0.f, ay = 0.f, az = 0.f;
  for (int j = s + q; j < e; j += 4) {
    int2 p = pairs[j];
    uint2 hv = *(const uint2*)(Ah + (size_t)p.x * 32 + kin * 4);
    float w = __int_as_float(p.y);
    ax += w * h2f(hv.x & 0xFFFFu);
    ay += w * h2f(hv.x >> 16);
    az += w * h2f(hv.y & 0xFFFFu);
  }
  ax += __shfl_xor(ax, 1); ay += __shfl_xor(ay, 1); az += __shfl_xor(az, 1);
  ax += __shfl_xor(ax, 2); ay += __shfl_xor(ay, 2); az += __shfl_xor(az, 2);
  if (q == 0) {
    float vx = scale * ax, vy = scale * ay, vz = scale * az;
    if (kprev >= 0) {
      uint2 pv = *(const uint2*)(Ah + (size_t)r * 32 + kprev * 4);
      vx -= h2f(pv.x & 0xFFFFu);
      vy -= h2f(pv.x >> 16);
      vz -= h2f(pv.y & 0xFFFFu);
    }
    uint2 sp = make_uint2(f2h(vx) | ((unsigned)f2h(vy) << 16), (unsigned)f2h(vz));
    *(uint2*)(Ah + (size_t)r * 32 + kout * 4) = sp;
  }
}

// h0 = relu(b0 + A[M,32]fp16 @ W0h[32,128]) via single-chunk MFMA; fp16 out
__global__ __launch_bounds__(256, 2) void h0_mfma_kernel(
    const ushort* __restrict__ Ah, const ushort* __restrict__ W0h,
    const float* __restrict__ b0, ushort* __restrict__ h0h, int M) {
  __shared__ ushort Al[64][40];
  __shared__ ushort Bl[128][40];
  __shared__ ushort Hs[64][128];
  const int tid = threadIdx.x;
  const int rowBase = blockIdx.x * 64;
  const int wave = tid >> 6;
  const int lane = tid & 63;
  const int m16 = lane & 15;
  const int quad = lane >> 4;
  {
    int sRow = tid >> 2;
    int sK8 = (tid & 3) * 8;
    int row = rowBase + sRow;
    uint4 av = make_uint4(0, 0, 0, 0);
    if (row < M) av = *(const uint4*)(Ah + (size_t)row * 32 + sK8);
    *(uint4*)&Al[sRow][sK8] = av;
  }
#pragma unroll
  for (int l = 0; l < 2; ++l) {
    int lin = tid + l * 256;
    int bRow = lin >> 2;
    int bK8 = (lin & 3) * 8;
    *(uint4*)&Bl[bRow][bK8] = *(const uint4*)(W0h + (size_t)bRow * 32 + bK8);
  }
  __syncthreads();
  short8 a = *(const short8*)&Al[wave * 16 + m16][quad * 8];
  floatx4 acc[8];
#pragma unroll
  for (int c = 0; c < 8; ++c) {
    floatx4 z;
    z[0] = 0.f; z[1] = 0.f; z[2] = 0.f; z[3] = 0.f;
    short8 b = *(const short8*)&Bl[c * 16 + m16][quad * 8];
    acc[c] = __builtin_amdgcn_mfma_f32_16x16x32_f16(a, b, z, 0, 0, 0);
  }
#pragma unroll
  for (int c = 0; c < 8; ++c) {
    int col = c * 16 + m16;
    float bv = b0[col];
#pragma unroll
    for (int r = 0; r < 4; ++r)
      Hs[wave * 16 + quad * 4 + r][col] = f2h(fmaxf(acc[c][r] + bv, 0.f));
  }
  __syncthreads();
  const uint4* ls = (const uint4*)&Hs[0][0];
  uint4* gd = (uint4*)(h0h + (size_t)rowBase * 128);
#pragma unroll
  for (int i = 0; i < 4; ++i) {
    int idx = tid + i * 256;
    if (rowBase + (idx >> 4) < M) gd[idx] = ls[idx];
  }
}

// ---------------- fused prep: weights(fp16) + degcnt zero + copyx + out init
__global__ void prep_all_kernel(const float* __restrict__ W0, const float* __restrict__ W1,
                                const float* __restrict__ W2, ushort* __restrict__ W0h,
                                ushort* __restrict__ Wt1, ushort* __restrict__ Wt2,
                                int* __restrict__ degcnt,
                                const float* __restrict__ x, ushort* __restrict__ Ah,
                                float* __restrict__ out, const float* __restrict__ linb) {
  int i = blockIdx.x * 256 + threadIdx.x;
  if (i < 768 * 128) {
    int k = i / 128, n = i - k * 128;
    Wt1[(size_t)n * 768 + k] = f2h(W1[i]);
  } else if (i < 768 * 128 + 768 * 256) {
    int i2 = i - 768 * 128;
    int k = i2 / 256, n = i2 - k * 256;
    Wt2[(size_t)n * 768 + k] = f2h(W2[i2]);
  } else if (i < WPREP_TOTAL) {
    int i3 = i - 768 * 128 - 768 * 256;
    int col = i3 >> 5, k = i3 & 31;
    int a = k >> 2, jj = k & 3;
    float v = (k < 24 && jj < 3) ? W0[(a * 3 + jj) * 128 + col] : 0.f;
    W0h[(size_t)col * 32 + k] = f2h(v);
  } else if (i < WPREP_TOTAL + DEG_TOTAL) {
    degcnt[i - WPREP_TOTAL] = 0;
  } else if (i < WPREP_TOTAL + DEG_TOTAL + cN0) {
    int r = i - (WPREP_TOTAL + DEG_TOTAL);
    float x0 = x[3 * r], x1 = x[3 * r + 1], x2 = x[3 * r + 2];
    uint4 z = make_uint4(0, 0, 0, 0);
    uint4 first = make_uint4(f2h(x0) | ((unsigned)f2h(x1) << 16), (unsigned)f2h(x2), 0, 0);
    uint4* p = (uint4*)(Ah + (size_t)r * 32);
    p[0] = first; p[1] = z; p[2] = z; p[3] = z;
  } else if (i < PREP_ALL_TOTAL) {
    int o = i - (WPREP_TOTAL + DEG_TOTAL + cN0);
    out[o] = linb[o];
  }
}

// ---------------- main GEMM (fp16 A/B; optional fp16-only output) --------
template <int RELU, int OUTH>
__global__ __launch_bounds__(256, 2) void gemm_mfma_kernel(
    const ushort* __restrict__ Th, const ushort* __restrict__ Wt,
    const float* __restrict__ bias, float* __restrict__ C, ushort* __restrict__ Ch,
    int M, int N) {
  __shared__ ushort Al[64][40];
  __shared__ ushort Bl[128][40];
  __shared__ ushort Hs[64][128];
  const int tid = threadIdx.x;
  const int rowBase = blockIdx.x * 64;
  const int colBase = blockIdx.y * 128;
  const int wave = tid >> 6;
  const int lane = tid & 63;
  const int m16 = lane & 15;
  const int quad = lane >> 4;
  const size_t Mstride = (size_t)M * 128;

  floatx4 acc[8];
#pragma unroll
  for (int c = 0; c < 8; ++c)
#pragma unroll
    for (int r = 0; r < 4; ++r) acc[c][r] = 0.f;

  const int sRow = tid >> 2;
  const int sK8 = (tid & 3) * 8;
  const int growA = rowBase + sRow;
  const bool aValid = growA < M;

  for (int kc = 0; kc < 24; ++kc) {
    uint4 av = make_uint4(0, 0, 0, 0);
    if (aValid)
      av = *(const uint4*)(Th + (size_t)(kc >> 2) * Mstride + (size_t)growA * 128
                           + ((kc & 3) << 5) + sK8);
    *(uint4*)&Al[sRow][sK8] = av;
#pragma unroll
    for (int l = 0; l < 2; ++l) {
      int lin = tid + l * 256;
      int bRow = lin >> 2;
      int bK8 = (lin & 3) * 8;
      *(uint4*)&Bl[bRow][bK8] =
          *(const uint4*)(Wt + (size_t)(colBase + bRow) * 768 + kc * 32 + bK8);
    }
    __syncthreads();

    short8 a = *(const short8*)&Al[wave * 16 + m16][quad * 8];
#pragma unroll
    for (int c = 0; c < 8; ++c) {
      short8 b = *(const short8*)&Bl[c * 16 + m16][quad * 8];
      acc[c] = __builtin_amdgcn_mfma_f32_16x16x32_f16(a, b, acc[c], 0, 0, 0);
    }
    __syncthreads();
  }

  if (OUTH) {
#pragma unroll
    for (int c = 0; c < 8; ++c) {
      int col = c * 16 + m16;
      float bv = bias[col];
#pragma unroll
      for (int r = 0; r < 4; ++r) {
        float v = acc[c][r] + bv;
        if (RELU) v = fmaxf(v, 0.f);
        Hs[wave * 16 + quad * 4 + r][col] = f2h(v);
      }
    }
    __syncthreads();
    const uint4* ls = (const uint4*)&Hs[0][0];
    uint4* gd = (uint4*)(Ch + (size_t)rowBase * 128);
#pragma unroll
    for (int i = 0; i < 4; ++i) {
      int idx = tid + i * 256;
      if (rowBase + (idx >> 4) < M) gd[idx] = ls[idx];
    }
  } else {
#pragma unroll
    for (int c = 0; c < 8; ++c) {
      int col = colBase + c * 16 + m16;
      float bv = bias[col];
#pragma unroll
      for (int r = 0; r < 4; ++r) {
        int row = rowBase + wave * 16 + quad * 4 + r;
        if (row < M) {
          float v = acc[c][r] + bv;
          if (RELU) v = fmaxf(v, 0.f);
          C[(size_t)row * N + col] = v;
        }
      }
    }
  }
}

// ---------------- linear head ----------------
__global__ __launch_bounds__(256) void linear_kernel(const float* __restrict__ Wl,
                                                     const float* __restrict__ h,
                                                     float* __restrict__ out, int D) {
  float p[10];
#pragma unroll
  for (int j = 0; j < 10; ++j) p[j] = 0.f;
  int stride = gridDim.x * blockDim.x;
  for (int i = blockIdx.x * blockDim.x + threadIdx.x; i < D; i += stride) {
    float hv = h[i];
#pragma unroll
    for (int j = 0; j < 10; ++j) p[j] += Wl[(size_t)j * D + i] * hv;
  }
#pragma unroll
  for (int j = 0; j < 10; ++j) {
#pragma unroll
    for (int off = 32; off > 0; off >>= 1) p[j] += __shfl_down(p[j], off, 64);
  }
  __shared__ float s[4][10];
  int wave = threadIdx.x >> 6, lane = threadIdx.x & 63;
  if (lane == 0) {
#pragma unroll
    for (int j = 0; j < 10; ++j) s[wave][j] = p[j];
  }
  __syncthreads();
  if (threadIdx.x < 10) {
    float t = s[0][threadIdx.x] + s[1][threadIdx.x] + s[2][threadIdx.x] + s[3][threadIdx.x];
    atomicAdd(&out[threadIdx.x], t);
  }
}

// ---------------- host orchestration ----------------
extern "C" void kernel_launch(void* const* d_in, const int* in_sizes, int n_in,
                              void* d_out, int out_size, void* d_ws, size_t ws_size,
                              hipStream_t stream) {
  const float* x    = (const float*)d_in[0];
  const int*   ei0  = (const int*)d_in[1];
  const int*   ei1  = (const int*)d_in[2];
  const int*   ei2  = (const int*)d_in[3];
  const float* W0   = (const float*)d_in[4];
  const float* b0   = (const float*)d_in[5];
  const float* W1   = (const float*)d_in[6];
  const float* b1   = (const float*)d_in[7];
  const float* W2   = (const float*)d_in[8];
  const float* b2   = (const float*)d_in[9];
  const int*   D0r  = (const int*)d_in[10];
  const int*   D0c  = (const int*)d_in[11];
  const float* D0v  = (const float*)d_in[12];
  const int*   D1r  = (const int*)d_in[13];
  const int*   D1c  = (const int*)d_in[14];
  const float* D1v  = (const float*)d_in[15];
  const float* linW = (const float*)d_in[16];
  const float* linb = (const float*)d_in[17];
  float* out = (float*)d_out;
  (void)in_sizes; (void)n_in; (void)out_size; (void)ws_size;

  const int* src0 = ei0;            const int* dst0 = ei0 + cE0;
  const int* src1 = ei1;            const int* dst1 = ei1 + cE1;
  const int* src2 = ei2;            const int* dst2 = ei2 + cE2;

  float* ws = (float*)d_ws;
  size_t off = 0;
  auto alloc = [&](size_t n) {
    float* p = ws + off;
    off += (n + 63) & ~size_t(63);
    return p;
  };
  float* dinv       = alloc(DEG_TOTAL);
  int*   degcnt     = (int*)alloc(DEG_TOTAL);
  int*   cntCB      = (int*)alloc((size_t)TCB * BSTRIDE);
  int*   bucketTot  = (int*)alloc(TB);
  int*   bucketBase = (int*)alloc(TB);
  int2*  scatPairs  = (int2*)alloc((size_t)2 * E_TOTAL);
  int2*  csrPairs   = (int2*)alloc((size_t)2 * E_TOTAL);
  int*   offArr     = (int*)alloc(NPAD_TOTAL);
  ushort* W0h       = (ushort*)alloc(128 * 32 / 2);
  ushort* Wt1       = (ushort*)alloc(768 * 128 / 2);
  ushort* Wt2       = (ushort*)alloc(768 * 256 / 2);
  ushort* Ah0       = (ushort*)alloc((size_t)cN0 * 16);      // [N0][32] fp16 state
  ushort* h0h       = (ushort*)alloc((size_t)cN0 * 64);      // [N0][128] fp16
  ushort* Th1       = (ushort*)alloc((size_t)6 * cN1 * 64);  // fp16-only state
  ushort* out1h     = (ushort*)alloc((size_t)cN1 * 64);
  float* Tlvl2      = alloc((size_t)6 * cN2 * 128);          // fp32 state (lvl2)
  ushort* Th2       = (ushort*)alloc((size_t)6 * cN2 * 64);
  float* out2       = alloc((size_t)cN2 * 256);

  auto nb = [](long long n) { return (unsigned)((n + 255) / 256); };

  // ---- fused prep ----
  prep_all_kernel<<<nb(PREP_ALL_TOTAL), 256, 0, stream>>>(
      W0, W1, W2, W0h, Wt1, Wt2, degcnt, x, Ah0, out, linb);

  // ---- two-phase radix CSR build ----
  c1_count_kernel<<<TCB, 256, 0, stream>>>(dst0, dst1, dst2, D0r, D1r,
                                           src0, src1, src2, degcnt, cntCB);
  c2a_scan_kernel<<<TB, 256, 0, stream>>>(cntCB, bucketTot, degcnt, dinv);
  c2b_scan_kernel<<<5, 256, 0, stream>>>(bucketTot, bucketBase);
  c3_dst_kernel<<<TCB, 256, 0, stream>>>(dst0, src0, dst1, src1, dst2, src2,
                                         D0r, D0c, D0v, D1r, D1c, D1v,
                                         dinv, cntCB, bucketBase, scatPairs);
  dcsr_kernel<<<TB, 256, 0, stream>>>(scatPairs, bucketTot, bucketBase,
                                      offArr, csrPairs);

  auto seg_off   = [&](int s) { return offArr + NBASE[s]; };
  auto seg_pairs = [&](int s) { return csrPairs + EBASE[s]; };

  // ================= Level 0 (fp16 state in Ah0 slots) =================
  csr_prop0_kernel<<<nb((size_t)4 * cN0), 256, 0, stream>>>(
      seg_off(0), seg_pairs(0), Ah0, 1.f, cN0, 0, 1, -1);
  csr_prop0_kernel<<<nb((size_t)4 * cN0), 256, 0, stream>>>(
      seg_off(0), seg_pairs(0), Ah0, 2.f, cN0, 1, 2, 0);
  csr_prop0_kernel<<<nb((size_t)4 * cN0), 256, 0, stream>>>(
      seg_off(0), seg_pairs(0), Ah0, 2.f, cN0, 2, 3, 1);
  csr_prop0_kernel<<<nb((size_t)4 * cN0), 256, 0, stream>>>(
      seg_off(0), seg_pairs(0), Ah0, 2.f, cN0, 3, 4, 2);
  csr_prop0_kernel<<<nb((size_t)4 * cN0), 256, 0, stream>>>(
      seg_off(0), seg_pairs(0), Ah0, 2.f, cN0, 4, 5, 3);

  // MFMA h0 (fp16 out), then pool0 -> Th1 slot 0 (fp16 only)
  h0_mfma_kernel<<<(cN0 + 63) / 64, 256, 0, stream>>>(Ah0, W0h, b0, h0h, cN0);
  csr_prop128h_kernel<<<(cN1 + 7) / 8, 256, 0, stream>>>(
      seg_off(3), seg_pairs(3), h0h, nullptr, Th1, nullptr, nullptr, 1.f, cN1);

  // ================= Level 1 (fp16-only state) =================
  {
    auto Thk = [&](int k) { return Th1 + (size_t)k * cN1 * 128; };
    auto prop = [&](int kin, int kout, int kprev, float scale) {
      csr_prop128h_kernel<<<(cN1 + 7) / 8, 256, 0, stream>>>(
          seg_off(1), seg_pairs(1), Thk(kin), nullptr, Thk(kout),
          nullptr, (kprev >= 0) ? Thk(kprev) : nullptr, scale, cN1);
    };
    prop(0, 1, -1, 1.f);
    prop(1, 2, 0, 2.f);
    prop(2, 3, 1, 2.f);
    prop(3, 4, 2, 2.f);
    prop(4, 5, 3, 2.f);
    dim3 g((cN1 + 63) / 64, 1);
    gemm_mfma_kernel<1, 1><<<g, 256, 0, stream>>>(Th1, Wt1, b1, nullptr, out1h,
                                                  cN1, 128);
  }

  // pool1: out1h -> Tlvl2 slot0 (fp32) + Th2 slot0 (fp16)
  csr_prop128h_kernel<<<(cN2 + 7) / 8, 256, 0, stream>>>(
      seg_off(4), seg_pairs(4), out1h, Tlvl2, Th2, nullptr, nullptr, 1.f, cN2);

  // ================= Level 2 (fp32 recurrence state kept) =================
  {
    auto Tk  = [&](int k) { return Tlvl2 + (size_t)k * cN2 * 128; };
    auto Thk = [&](int k) { return Th2 + (size_t)k * cN2 * 128; };
    auto prop = [&](int kin, int kout, int kprev, float scale, bool needF32) {
      csr_prop128h_kernel<<<(cN2 + 7) / 8, 256, 0, stream>>>(
          seg_off(2), seg_pairs(2), Thk(kin), needF32 ? Tk(kout) : nullptr, Thk(kout),
          (kprev >= 0) ? Tk(kprev) : nullptr, nullptr, scale, cN2);
    };
    prop(0, 1, -1, 1.f, true);
    prop(1, 2, 0, 2.f, true);
    prop(2, 3, 1, 2.f, true);
    prop(3, 4, 2, 2.f, true);
    prop(4, 5, 3, 2.f, false);
    dim3 g((cN2 + 63) / 64, 2);
    gemm_mfma_kernel<0, 0><<<g, 256, 0, stream>>>(Th2, Wt2, b2, out2, nullptr,
                                                  cN2, 256);
  }

  // ---- linear head (out pre-initialized with linb in prep) ----
  linear_kernel<<<512, 256, 0, stream>>>(linW, out2, out, cD);
}

// Round 8
// 409.177 us; speedup vs baseline: 1.0824x; 1.0824x over previous
//
#include <hip/hip_runtime.h>

// ChebClassifier R17: R15 base (fp32 recurrence state everywhere, fp16
// gather side-channel, two-phase radix CSR) + csr_prop128h reworked from
// 32 lanes x 8B to 16 lanes x 16B (uint4) per row: half the gather
// instructions, 4 rows/wave, 64B/lane in flight on the 4-edge unroll.
// R16's fp16-state reverted (cache-line density regression, absmax 0.031).
// Math bit-identical to R15 (per-channel edge-accumulation order unchanged).

namespace {
constexpr int cN0 = 100000, cN1 = 25000, cN2 = 6250;
constexpr int cE0 = 600000, cE1 = 150000, cE2 = 37500;
constexpr int cD  = cN2 * 256;

// jobs 0-4: dst-keyed CSR builds (conv0, conv1, conv2, pool0, pool1)
constexpr int JN[5]  = {cN0, cN1, cN2, cN1, cN2};
constexpr int JE[5]  = {cE0, cE1, cE2, 100000, 25000};
constexpr int JB[5]  = {391, 98, 25, 98, 25};
constexpr int JBBASE[6] = {0, 391, 489, 514, 612, 637};
constexpr int TB = 637;
constexpr int JCB[5] = {293, 74, 19, 49, 13};
constexpr int JCBASE[6] = {0, 293, 367, 386, 435, 448};
constexpr int TCB = 448;
constexpr int CHUNK = 2048;
constexpr int BSTRIDE = 400;

constexpr int EBASE[5]   = {0, 600000, 750000, 787500, 887500};
constexpr int E_TOTAL    = 912500;
constexpr int NBASE[5]   = {0, 100096, 125184, 131584, 156672};
constexpr int NPAD_TOTAL = 163072;
constexpr int DEGBASE[3] = {0, 100000, 125000};
constexpr int DEG_TOTAL  = 131250;
constexpr int WPREP_TOTAL = 768 * 128 + 768 * 256 + 128 * 32;
constexpr int PREP_ALL_TOTAL = WPREP_TOTAL + DEG_TOTAL + cN0 + 10;
}

typedef __attribute__((ext_vector_type(8))) short short8;
typedef __attribute__((ext_vector_type(4))) float floatx4;

__device__ inline ushort f2h(float f) {
  union { _Float16 h; ushort u; } v;
  v.h = (_Float16)f;
  return v.u;
}
__device__ inline float h2f(unsigned lo16) {
  union { ushort u; _Float16 h; } v;
  v.u = (ushort)lo16;
  return (float)v.h;
}

__device__ inline int job_of_cb(int cb) {
  int j = 0;
  while (cb >= JCBASE[j + 1]) ++j;
  return j;
}
__device__ inline int job_of_bucket(int g) {
  int j = 0;
  while (g >= JBBASE[j + 1]) ++j;
  return j;
}

// ---------------- two-phase radix CSR build (R12/R15) ----------------
__global__ __launch_bounds__(256) void c1_count_kernel(
    const int* __restrict__ k0, const int* __restrict__ k1, const int* __restrict__ k2,
    const int* __restrict__ k3, const int* __restrict__ k4,
    const int* __restrict__ s0, const int* __restrict__ s1, const int* __restrict__ s2,
    int* __restrict__ degcnt, int* __restrict__ cntCB) {
  __shared__ int cnt[BSTRIDE];
  int cb = blockIdx.x;
  int j = job_of_cb(cb);
  int lb = cb - JCBASE[j];
  const int* keys;
  const int* srck = nullptr;
  int dbase = 0;
  switch (j) {
    case 0: keys = k0; srck = s0; dbase = DEGBASE[0]; break;
    case 1: keys = k1; srck = s1; dbase = DEGBASE[1]; break;
    case 2: keys = k2; srck = s2; dbase = DEGBASE[2]; break;
    case 3: keys = k3; break;
    default: keys = k4; break;
  }
  int nB = JB[j];
  for (int b = threadIdx.x; b < nB; b += 256) cnt[b] = 0;
  __syncthreads();
  int e0 = lb * CHUNK;
  int e1 = min(e0 + CHUNK, JE[j]);
  for (int e = e0 + threadIdx.x; e < e1; e += 256) {
    atomicAdd(&cnt[keys[e] >> 8], 1);
    if (srck) atomicAdd(&degcnt[dbase + srck[e]], 1);
  }
  __syncthreads();
  for (int b = threadIdx.x; b < nB; b += 256)
    cntCB[cb * BSTRIDE + b] = cnt[b];
}

__global__ __launch_bounds__(256) void c2a_scan_kernel(int* __restrict__ cntCB,
                                                       int* __restrict__ bucketTot,
                                                       const int* __restrict__ degcnt,
                                                       float* __restrict__ dinv) {
  __shared__ int s[256];
  int g = blockIdx.x;
  int j = job_of_bucket(g);
  int b = g - JBBASE[j];
  int cb0 = JCBASE[j], nCB = JCB[j];
  int carry = 0;
  for (int c0 = 0; c0 < nCB; c0 += 256) {
    int i = c0 + threadIdx.x;
    int v = (i < nCB) ? cntCB[(cb0 + i) * BSTRIDE + b] : 0;
    s[threadIdx.x] = v;
    __syncthreads();
    for (int d = 1; d < 256; d <<= 1) {
      int t = (threadIdx.x >= d) ? s[threadIdx.x - d] : 0;
      __syncthreads();
      s[threadIdx.x] += t;
      __syncthreads();
    }
    if (i < nCB) cntCB[(cb0 + i) * BSTRIDE + b] = carry + s[threadIdx.x] - v;
    carry += s[255];
    __syncthreads();
  }
  if (threadIdx.x == 0) bucketTot[g] = carry;
  int idx = blockIdx.x * 256 + threadIdx.x;
  if (idx < DEG_TOTAL) {
    int c = degcnt[idx];
    dinv[idx] = (c > 0) ? rsqrtf((float)c) : 0.f;
  }
}

__global__ __launch_bounds__(256) void c2b_scan_kernel(const int* __restrict__ bucketTot,
                                                       int* __restrict__ bucketBase) {
  __shared__ int s[256];
  int j = blockIdx.x;
  int g0 = JBBASE[j], nB = JB[j];
  int carry = 0;
  for (int c0 = 0; c0 < nB; c0 += 256) {
    int i = c0 + threadIdx.x;
    int v = (i < nB) ? bucketTot[g0 + i] : 0;
    s[threadIdx.x] = v;
    __syncthreads();
    for (int d = 1; d < 256; d <<= 1) {
      int t = (threadIdx.x >= d) ? s[threadIdx.x - d] : 0;
      __syncthreads();
      s[threadIdx.x] += t;
      __syncthreads();
    }
    if (i < nB) bucketBase[g0 + i] = carry + s[threadIdx.x] - v;
    carry += s[255];
    __syncthreads();
  }
}

__global__ __launch_bounds__(256) void c3_dst_kernel(
    const int* __restrict__ d0, const int* __restrict__ s0,
    const int* __restrict__ d1, const int* __restrict__ s1,
    const int* __restrict__ d2, const int* __restrict__ s2,
    const int* __restrict__ p0r, const int* __restrict__ p0c, const float* __restrict__ p0v,
    const int* __restrict__ p1r, const int* __restrict__ p1c, const float* __restrict__ p1v,
    const float* __restrict__ dinv,
    const int* __restrict__ cntCB, const int* __restrict__ bucketBase,
    int2* __restrict__ scatPairs) {
  __shared__ int base[BSTRIDE];
  int cb = blockIdx.x;
  int j = job_of_cb(cb);
  int lb = cb - JCBASE[j];
  const int* dk; const int* sk; const float* vv = nullptr;
  switch (j) {
    case 0: dk = d0; sk = s0; break;
    case 1: dk = d1; sk = s1; break;
    case 2: dk = d2; sk = s2; break;
    case 3: dk = p0r; sk = p0c; vv = p0v; break;
    default: dk = p1r; sk = p1c; vv = p1v; break;
  }
  int nB = JB[j];
  for (int b = threadIdx.x; b < nB; b += 256)
    base[b] = EBASE[j] + bucketBase[JBBASE[j] + b] + cntCB[cb * BSTRIDE + b];
  __syncthreads();
  int e0 = lb * CHUNK;
  int e1 = min(e0 + CHUNK, JE[j]);
  for (int e = e0 + threadIdx.x; e < e1; e += 256) {
    int d = dk[e];
    int s = sk[e];
    float w;
    if (j < 3) w = -(dinv[DEGBASE[j] + s] * dinv[DEGBASE[j] + d]);
    else w = vv[e];
    int pos = atomicAdd(&base[d >> 8], 1);
    scatPairs[pos] = make_int2(((d & 255) << 17) | s, __float_as_int(w));
  }
}

__global__ __launch_bounds__(256) void dcsr_kernel(const int2* __restrict__ scatPairs,
                                                   const int* __restrict__ bucketTot,
                                                   const int* __restrict__ bucketBase,
                                                   int* __restrict__ off,
                                                   int2* __restrict__ csrPairs) {
  __shared__ int cnt[256];
  __shared__ int sArr[256];
  __shared__ int cur[256];
  int g = blockIdx.x;
  int j = job_of_bucket(g);
  int b = g - JBBASE[j];
  int relBase = bucketBase[g];
  int st = EBASE[j] + relBase;
  int en = st + bucketTot[g];
  cnt[threadIdx.x] = 0;
  __syncthreads();
  for (int idx = st + threadIdx.x; idx < en; idx += 256)
    atomicAdd(&cnt[scatPairs[idx].x >> 17], 1);
  __syncthreads();
  int v = cnt[threadIdx.x];
  sArr[threadIdx.x] = v;
  __syncthreads();
  for (int d = 1; d < 256; d <<= 1) {
    int t = (threadIdx.x >= d) ? sArr[threadIdx.x - d] : 0;
    __syncthreads();
    sArr[threadIdx.x] += t;
    __syncthreads();
  }
  int excl = sArr[threadIdx.x] - v;
  int node = b * 256 + threadIdx.x;
  if (node < JN[j]) off[NBASE[j] + node] = relBase + excl;
  if (threadIdx.x == 0 && b == JB[j] - 1) off[NBASE[j] + JN[j]] = JE[j];
  cur[threadIdx.x] = st + excl;
  __syncthreads();
  for (int idx = st + threadIdx.x; idx < en; idx += 256) {
    int2 p = scatPairs[idx];
    int dl = p.x >> 17;
    int s = p.x & 0x1FFFF;
    int pos = atomicAdd(&cur[dl], 1);
    csrPairs[pos] = make_int2(s, p.y);
  }
}

// ---------------- unified prop/pool: 16 lanes x uint4 per 128-wide row ----
// Gathers fp16 rows hh[.][128] (16B/lane); fp32 accumulate; optional fp32
// prev subtract; optional fp32 y; always fp16 yh.
__global__ __launch_bounds__(256) void csr_prop128h_kernel(
    const int* __restrict__ off, const int2* __restrict__ pairs,
    const ushort* __restrict__ hh, float* __restrict__ y, ushort* __restrict__ yh,
    const float* __restrict__ prev, float scale, int N) {
  int r = blockIdx.x * 16 + (threadIdx.x >> 4);
  int l = threadIdx.x & 15;
  if (r >= N) return;
  int s = off[r], e = off[r + 1];
  const uint4* h4 = (const uint4*)hh;   // 8 halves per lane
  float a0 = 0.f, a1 = 0.f, a2 = 0.f, a3 = 0.f;
  float a4 = 0.f, a5 = 0.f, a6 = 0.f, a7 = 0.f;
  int j = s;
  for (; j + 4 <= e; j += 4) {
    int2 p0 = pairs[j], p1 = pairs[j + 1], p2 = pairs[j + 2], p3 = pairs[j + 3];
    uint4 v0 = h4[(size_t)p0.x * 16 + l];
    uint4 v1 = h4[(size_t)p1.x * 16 + l];
    uint4 v2 = h4[(size_t)p2.x * 16 + l];
    uint4 v3 = h4[(size_t)p3.x * 16 + l];
    float w0 = __int_as_float(p0.y), w1 = __int_as_float(p1.y);
    float w2 = __int_as_float(p2.y), w3 = __int_as_float(p3.y);
    a0 += w0 * h2f(v0.x & 0xFFFFu) + w1 * h2f(v1.x & 0xFFFFu)
        + w2 * h2f(v2.x & 0xFFFFu) + w3 * h2f(v3.x & 0xFFFFu);
    a1 += w0 * h2f(v0.x >> 16) + w1 * h2f(v1.x >> 16)
        + w2 * h2f(v2.x >> 16) + w3 * h2f(v3.x >> 16);
    a2 += w0 * h2f(v0.y & 0xFFFFu) + w1 * h2f(v1.y & 0xFFFFu)
        + w2 * h2f(v2.y & 0xFFFFu) + w3 * h2f(v3.y & 0xFFFFu);
    a3 += w0 * h2f(v0.y >> 16) + w1 * h2f(v1.y >> 16)
        + w2 * h2f(v2.y >> 16) + w3 * h2f(v3.y >> 16);
    a4 += w0 * h2f(v0.z & 0xFFFFu) + w1 * h2f(v1.z & 0xFFFFu)
        + w2 * h2f(v2.z & 0xFFFFu) + w3 * h2f(v3.z & 0xFFFFu);
    a5 += w0 * h2f(v0.z >> 16) + w1 * h2f(v1.z >> 16)
        + w2 * h2f(v2.z >> 16) + w3 * h2f(v3.z >> 16);
    a6 += w0 * h2f(v0.w & 0xFFFFu) + w1 * h2f(v1.w & 0xFFFFu)
        + w2 * h2f(v2.w & 0xFFFFu) + w3 * h2f(v3.w & 0xFFFFu);
    a7 += w0 * h2f(v0.w >> 16) + w1 * h2f(v1.w >> 16)
        + w2 * h2f(v2.w >> 16) + w3 * h2f(v3.w >> 16);
  }
  for (; j < e; ++j) {
    int2 p = pairs[j];
    uint4 v0 = h4[(size_t)p.x * 16 + l];
    float w = __int_as_float(p.y);
    a0 += w * h2f(v0.x & 0xFFFFu);
    a1 += w * h2f(v0.x >> 16);
    a2 += w * h2f(v0.y & 0xFFFFu);
    a3 += w * h2f(v0.y >> 16);
    a4 += w * h2f(v0.z & 0xFFFFu);
    a5 += w * h2f(v0.z >> 16);
    a6 += w * h2f(v0.w & 0xFFFFu);
    a7 += w * h2f(v0.w >> 16);
  }
  a0 *= scale; a1 *= scale; a2 *= scale; a3 *= scale;
  a4 *= scale; a5 *= scale; a6 *= scale; a7 *= scale;
  if (prev) {
    const float4* p4 = (const float4*)prev;
    float4 pa = p4[(size_t)r * 32 + 2 * l];
    float4 pb = p4[(size_t)r * 32 + 2 * l + 1];
    a0 -= pa.x; a1 -= pa.y; a2 -= pa.z; a3 -= pa.w;
    a4 -= pb.x; a5 -= pb.y; a6 -= pb.z; a7 -= pb.w;
  }
  if (y) {
    float4* y4 = (float4*)y;
    y4[(size_t)r * 32 + 2 * l]     = make_float4(a0, a1, a2, a3);
    y4[(size_t)r * 32 + 2 * l + 1] = make_float4(a4, a5, a6, a7);
  }
  uint4 sp;
  sp.x = f2h(a0) | ((unsigned)f2h(a1) << 16);
  sp.y = f2h(a2) | ((unsigned)f2h(a3) << 16);
  sp.z = f2h(a4) | ((unsigned)f2h(a5) << 16);
  sp.w = f2h(a6) | ((unsigned)f2h(a7) << 16);
  ((uint4*)yh)[(size_t)r * 16 + l] = sp;
}

// level-0: 4 lanes per row, quad shuffle reduce; fp32 slab + fp16 slot kout
__global__ __launch_bounds__(256) void csr_prop3_kernel(
    const int* __restrict__ off, const int2* __restrict__ pairs,
    const float4* __restrict__ h, float4* __restrict__ y,
    const float4* __restrict__ prev, float scale, int N,
    ushort* __restrict__ yh, int kout) {
  int t = blockIdx.x * 256 + threadIdx.x;
  int r = t >> 2;
  int q = t & 3;
  if (r >= N) return;
  int s = off[r], e = off[r + 1];
  float ax = 0.f, ay = 0.f, az = 0.f;
  for (int j = s + q; j < e; j += 4) {
    int2 p = pairs[j];
    float4 hv = h[p.x];
    float w = __int_as_float(p.y);
    ax += w * hv.x; ay += w * hv.y; az += w * hv.z;
  }
  ax += __shfl_xor(ax, 1); ay += __shfl_xor(ay, 1); az += __shfl_xor(az, 1);
  ax += __shfl_xor(ax, 2); ay += __shfl_xor(ay, 2); az += __shfl_xor(az, 2);
  if (q == 0) {
    float4 v = make_float4(scale * ax, scale * ay, scale * az, 0.f);
    if (prev) {
      float4 pv = prev[r];
      v.x -= pv.x; v.y -= pv.y; v.z -= pv.z;
    }
    y[r] = v;
    uint2 sp = make_uint2(f2h(v.x) | ((unsigned)f2h(v.y) << 16), (unsigned)f2h(v.z));
    *(uint2*)(yh + (size_t)r * 32 + kout * 4) = sp;
  }
}

// h0 = relu(b0 + A[M,32]fp16 @ W0h[32,128]) via single-chunk MFMA; fp16 out
__global__ __launch_bounds__(256, 2) void h0_mfma_kernel(
    const ushort* __restrict__ Ah, const ushort* __restrict__ W0h,
    const float* __restrict__ b0, ushort* __restrict__ h0h, int M) {
  __shared__ ushort Al[64][40];
  __shared__ ushort Bl[128][40];
  __shared__ ushort Hs[64][128];
  const int tid = threadIdx.x;
  const int rowBase = blockIdx.x * 64;
  const int wave = tid >> 6;
  const int lane = tid & 63;
  const int m16 = lane & 15;
  const int quad = lane >> 4;
  {
    int sRow = tid >> 2;
    int sK8 = (tid & 3) * 8;
    int row = rowBase + sRow;
    uint4 av = make_uint4(0, 0, 0, 0);
    if (row < M) av = *(const uint4*)(Ah + (size_t)row * 32 + sK8);
    *(uint4*)&Al[sRow][sK8] = av;
  }
#pragma unroll
  for (int l = 0; l < 2; ++l) {
    int lin = tid + l * 256;
    int bRow = lin >> 2;
    int bK8 = (lin & 3) * 8;
    *(uint4*)&Bl[bRow][bK8] = *(const uint4*)(W0h + (size_t)bRow * 32 + bK8);
  }
  __syncthreads();
  short8 a = *(const short8*)&Al[wave * 16 + m16][quad * 8];
  floatx4 acc[8];
#pragma unroll
  for (int c = 0; c < 8; ++c) {
    floatx4 z;
    z[0] = 0.f; z[1] = 0.f; z[2] = 0.f; z[3] = 0.f;
    short8 b = *(const short8*)&Bl[c * 16 + m16][quad * 8];
    acc[c] = __builtin_amdgcn_mfma_f32_16x16x32_f16(a, b, z, 0, 0, 0);
  }
#pragma unroll
  for (int c = 0; c < 8; ++c) {
    int col = c * 16 + m16;
    float bv = b0[col];
#pragma unroll
    for (int r = 0; r < 4; ++r)
      Hs[wave * 16 + quad * 4 + r][col] = f2h(fmaxf(acc[c][r] + bv, 0.f));
  }
  __syncthreads();
  const uint4* ls = (const uint4*)&Hs[0][0];
  uint4* gd = (uint4*)(h0h + (size_t)rowBase * 128);
#pragma unroll
  for (int i = 0; i < 4; ++i) {
    int idx = tid + i * 256;
    if (rowBase + (idx >> 4) < M) gd[idx] = ls[idx];
  }
}

// ---------------- fused prep: weights(fp16) + degcnt zero + copyx + out init
__global__ void prep_all_kernel(const float* __restrict__ W0, const float* __restrict__ W1,
                                const float* __restrict__ W2, ushort* __restrict__ W0h,
                                ushort* __restrict__ Wt1, ushort* __restrict__ Wt2,
                                int* __restrict__ degcnt,
                                const float* __restrict__ x, float4* __restrict__ Tb,
                                ushort* __restrict__ Ah,
                                float* __restrict__ out, const float* __restrict__ linb) {
  int i = blockIdx.x * 256 + threadIdx.x;
  if (i < 768 * 128) {
    int k = i / 128, n = i - k * 128;
    Wt1[(size_t)n * 768 + k] = f2h(W1[i]);
  } else if (i < 768 * 128 + 768 * 256) {
    int i2 = i - 768 * 128;
    int k = i2 / 256, n = i2 - k * 256;
    Wt2[(size_t)n * 768 + k] = f2h(W2[i2]);
  } else if (i < WPREP_TOTAL) {
    int i3 = i - 768 * 128 - 768 * 256;
    int col = i3 >> 5, k = i3 & 31;
    int a = k >> 2, jj = k & 3;
    float v = (k < 24 && jj < 3) ? W0[(a * 3 + jj) * 128 + col] : 0.f;
    W0h[(size_t)col * 32 + k] = f2h(v);
  } else if (i < WPREP_TOTAL + DEG_TOTAL) {
    degcnt[i - WPREP_TOTAL] = 0;
  } else if (i < WPREP_TOTAL + DEG_TOTAL + cN0) {
    int r = i - (WPREP_TOTAL + DEG_TOTAL);
    float x0 = x[3 * r], x1 = x[3 * r + 1], x2 = x[3 * r + 2];
    Tb[r] = make_float4(x0, x1, x2, 0.f);
    uint4 z = make_uint4(0, 0, 0, 0);
    uint4 first = make_uint4(f2h(x0) | ((unsigned)f2h(x1) << 16), (unsigned)f2h(x2), 0, 0);
    uint4* p = (uint4*)(Ah + (size_t)r * 32);
    p[0] = first; p[1] = z; p[2] = z; p[3] = z;
  } else if (i < PREP_ALL_TOTAL) {
    int o = i - (WPREP_TOTAL + DEG_TOTAL + cN0);
    out[o] = linb[o];
  }
}

// ---------------- main GEMM (fp16 A/B; optional fp16-only output) --------
template <int RELU, int OUTH>
__global__ __launch_bounds__(256, 2) void gemm_mfma_kernel(
    const ushort* __restrict__ Th, const ushort* __restrict__ Wt,
    const float* __restrict__ bias, float* __restrict__ C, ushort* __restrict__ Ch,
    int M, int N) {
  __shared__ ushort Al[64][40];
  __shared__ ushort Bl[128][40];
  __shared__ ushort Hs[64][128];
  const int tid = threadIdx.x;
  const int rowBase = blockIdx.x * 64;
  const int colBase = blockIdx.y * 128;
  const int wave = tid >> 6;
  const int lane = tid & 63;
  const int m16 = lane & 15;
  const int quad = lane >> 4;
  const size_t Mstride = (size_t)M * 128;

  floatx4 acc[8];
#pragma unroll
  for (int c = 0; c < 8; ++c)
#pragma unroll
    for (int r = 0; r < 4; ++r) acc[c][r] = 0.f;

  const int sRow = tid >> 2;
  const int sK8 = (tid & 3) * 8;
  const int growA = rowBase + sRow;
  const bool aValid = growA < M;

  for (int kc = 0; kc < 24; ++kc) {
    uint4 av = make_uint4(0, 0, 0, 0);
    if (aValid)
      av = *(const uint4*)(Th + (size_t)(kc >> 2) * Mstride + (size_t)growA * 128
                           + ((kc & 3) << 5) + sK8);
    *(uint4*)&Al[sRow][sK8] = av;
#pragma unroll
    for (int l = 0; l < 2; ++l) {
      int lin = tid + l * 256;
      int bRow = lin >> 2;
      int bK8 = (lin & 3) * 8;
      *(uint4*)&Bl[bRow][bK8] =
          *(const uint4*)(Wt + (size_t)(colBase + bRow) * 768 + kc * 32 + bK8);
    }
    __syncthreads();

    short8 a = *(const short8*)&Al[wave * 16 + m16][quad * 8];
#pragma unroll
    for (int c = 0; c < 8; ++c) {
      short8 b = *(const short8*)&Bl[c * 16 + m16][quad * 8];
      acc[c] = __builtin_amdgcn_mfma_f32_16x16x32_f16(a, b, acc[c], 0, 0, 0);
    }
    __syncthreads();
  }

  if (OUTH) {
#pragma unroll
    for (int c = 0; c < 8; ++c) {
      int col = c * 16 + m16;
      float bv = bias[col];
#pragma unroll
      for (int r = 0; r < 4; ++r) {
        float v = acc[c][r] + bv;
        if (RELU) v = fmaxf(v, 0.f);
        Hs[wave * 16 + quad * 4 + r][col] = f2h(v);
      }
    }
    __syncthreads();
    const uint4* ls = (const uint4*)&Hs[0][0];
    uint4* gd = (uint4*)(Ch + (size_t)rowBase * 128);
#pragma unroll
    for (int i = 0; i < 4; ++i) {
      int idx = tid + i * 256;
      if (rowBase + (idx >> 4) < M) gd[idx] = ls[idx];
    }
  } else {
#pragma unroll
    for (int c = 0; c < 8; ++c) {
      int col = colBase + c * 16 + m16;
      float bv = bias[col];
#pragma unroll
      for (int r = 0; r < 4; ++r) {
        int row = rowBase + wave * 16 + quad * 4 + r;
        if (row < M) {
          float v = acc[c][r] + bv;
          if (RELU) v = fmaxf(v, 0.f);
          C[(size_t)row * N + col] = v;
        }
      }
    }
  }
}

// ---------------- linear head ----------------
__global__ __launch_bounds__(256) void linear_kernel(const float* __restrict__ Wl,
                                                     const float* __restrict__ h,
                                                     float* __restrict__ out, int D) {
  float p[10];
#pragma unroll
  for (int j = 0; j < 10; ++j) p[j] = 0.f;
  int stride = gridDim.x * blockDim.x;
  for (int i = blockIdx.x * blockDim.x + threadIdx.x; i < D; i += stride) {
    float hv = h[i];
#pragma unroll
    for (int j = 0; j < 10; ++j) p[j] += Wl[(size_t)j * D + i] * hv;
  }
#pragma unroll
  for (int j = 0; j < 10; ++j) {
#pragma unroll
    for (int off = 32; off > 0; off >>= 1) p[j] += __shfl_down(p[j], off, 64);
  }
  __shared__ float s[4][10];
  int wave = threadIdx.x >> 6, lane = threadIdx.x & 63;
  if (lane == 0) {
#pragma unroll
    for (int j = 0; j < 10; ++j) s[wave][j] = p[j];
  }
  __syncthreads();
  if (threadIdx.x < 10) {
    float t = s[0][threadIdx.x] + s[1][threadIdx.x] + s[2][threadIdx.x] + s[3][threadIdx.x];
    atomicAdd(&out[threadIdx.x], t);
  }
}

// ---------------- host orchestration ----------------
extern "C" void kernel_launch(void* const* d_in, const int* in_sizes, int n_in,
                              void* d_out, int out_size, void* d_ws, size_t ws_size,
                              hipStream_t stream) {
  const float* x    = (const float*)d_in[0];
  const int*   ei0  = (const int*)d_in[1];
  const int*   ei1  = (const int*)d_in[2];
  const int*   ei2  = (const int*)d_in[3];
  const float* W0   = (const float*)d_in[4];
  const float* b0   = (const float*)d_in[5];
  const float* W1   = (const float*)d_in[6];
  const float* b1   = (const float*)d_in[7];
  const float* W2   = (const float*)d_in[8];
  const float* b2   = (const float*)d_in[9];
  const int*   D0r  = (const int*)d_in[10];
  const int*   D0c  = (const int*)d_in[11];
  const float* D0v  = (const float*)d_in[12];
  const int*   D1r  = (const int*)d_in[13];
  const int*   D1c  = (const int*)d_in[14];
  const float* D1v  = (const float*)d_in[15];
  const float* linW = (const float*)d_in[16];
  const float* linb = (const float*)d_in[17];
  float* out = (float*)d_out;
  (void)in_sizes; (void)n_in; (void)out_size; (void)ws_size;

  const int* src0 = ei0;            const int* dst0 = ei0 + cE0;
  const int* src1 = ei1;            const int* dst1 = ei1 + cE1;
  const int* src2 = ei2;            const int* dst2 = ei2 + cE2;

  float* ws = (float*)d_ws;
  size_t off = 0;
  auto alloc = [&](size_t n) {
    float* p = ws + off;
    off += (n + 63) & ~size_t(63);
    return p;
  };
  float* dinv       = alloc(DEG_TOTAL);
  int*   degcnt     = (int*)alloc(DEG_TOTAL);
  int*   cntCB      = (int*)alloc((size_t)TCB * BSTRIDE);
  int*   bucketTot  = (int*)alloc(TB);
  int*   bucketBase = (int*)alloc(TB);
  int2*  scatPairs  = (int2*)alloc((size_t)2 * E_TOTAL);
  int2*  csrPairs   = (int2*)alloc((size_t)2 * E_TOTAL);
  int*   offArr     = (int*)alloc(NPAD_TOTAL);
  ushort* W0h       = (ushort*)alloc(128 * 32 / 2);
  ushort* Wt1       = (ushort*)alloc(768 * 128 / 2);
  ushort* Wt2       = (ushort*)alloc(768 * 256 / 2);
  float4* Tb0       = (float4*)alloc((size_t)6 * cN0 * 4);
  ushort* Ah0       = (ushort*)alloc((size_t)cN0 * 16);
  ushort* h0h       = (ushort*)alloc((size_t)cN0 * 64);
  float* Tlvl1      = alloc((size_t)6 * cN1 * 128);
  ushort* Th1       = (ushort*)alloc((size_t)6 * cN1 * 64);
  ushort* out1h     = (ushort*)alloc((size_t)cN1 * 64);
  float* Tlvl2      = alloc((size_t)6 * cN2 * 128);
  ushort* Th2       = (ushort*)alloc((size_t)6 * cN2 * 64);
  float* out2       = alloc((size_t)cN2 * 256);

  auto nb = [](long long n) { return (unsigned)((n + 255) / 256); };

  // ---- fused prep: weights + degcnt zero + copyx + out init ----
  prep_all_kernel<<<nb(PREP_ALL_TOTAL), 256, 0, stream>>>(
      W0, W1, W2, W0h, Wt1, Wt2, degcnt, x, Tb0, Ah0, out, linb);

  // ---- two-phase radix CSR build ----
  c1_count_kernel<<<TCB, 256, 0, stream>>>(dst0, dst1, dst2, D0r, D1r,
                                           src0, src1, src2, degcnt, cntCB);
  c2a_scan_kernel<<<TB, 256, 0, stream>>>(cntCB, bucketTot, degcnt, dinv);
  c2b_scan_kernel<<<5, 256, 0, stream>>>(bucketTot, bucketBase);
  c3_dst_kernel<<<TCB, 256, 0, stream>>>(dst0, src0, dst1, src1, dst2, src2,
                                         D0r, D0c, D0v, D1r, D1c, D1v,
                                         dinv, cntCB, bucketBase, scatPairs);
  dcsr_kernel<<<TB, 256, 0, stream>>>(scatPairs, bucketTot, bucketBase,
                                      offArr, csrPairs);

  auto seg_off   = [&](int s) { return offArr + NBASE[s]; };
  auto seg_pairs = [&](int s) { return csrPairs + EBASE[s]; };

  // ================= Level 0 (F=3 -> 128), 4 lanes/row =================
  {
    auto Tk = [&](int k) { return Tb0 + (size_t)k * cN0; };
    csr_prop3_kernel<<<nb((size_t)4 * cN0), 256, 0, stream>>>(seg_off(0), seg_pairs(0),
        Tk(0), Tk(1), nullptr, 1.f, cN0, Ah0, 1);
    csr_prop3_kernel<<<nb((size_t)4 * cN0), 256, 0, stream>>>(seg_off(0), seg_pairs(0),
        Tk(1), Tk(2), Tk(0), 2.f, cN0, Ah0, 2);
    csr_prop3_kernel<<<nb((size_t)4 * cN0), 256, 0, stream>>>(seg_off(0), seg_pairs(0),
        Tk(2), Tk(3), Tk(1), 2.f, cN0, Ah0, 3);
    csr_prop3_kernel<<<nb((size_t)4 * cN0), 256, 0, stream>>>(seg_off(0), seg_pairs(0),
        Tk(3), Tk(4), Tk(2), 2.f, cN0, Ah0, 4);
    csr_prop3_kernel<<<nb((size_t)4 * cN0), 256, 0, stream>>>(seg_off(0), seg_pairs(0),
        Tk(4), Tk(5), Tk(3), 2.f, cN0, Ah0, 5);
  }
  // MFMA h0 (fp16 out), then pool0 fp16 gather -> Tlvl1 block 0
  h0_mfma_kernel<<<(cN0 + 63) / 64, 256, 0, stream>>>(Ah0, W0h, b0, h0h, cN0);
  csr_prop128h_kernel<<<(cN1 + 15) / 16, 256, 0, stream>>>(
      seg_off(3), seg_pairs(3), h0h, Tlvl1, Th1, nullptr, 1.f, cN1);

  // ================= Level 1 =================
  {
    auto Tk  = [&](int k) { return Tlvl1 + (size_t)k * cN1 * 128; };
    auto Thk = [&](int k) { return Th1 + (size_t)k * cN1 * 128; };
    auto prop = [&](int kin, int kout, int kprev, float scale, bool needF32) {
      csr_prop128h_kernel<<<(cN1 + 15) / 16, 256, 0, stream>>>(
          seg_off(1), seg_pairs(1), Thk(kin), needF32 ? Tk(kout) : nullptr, Thk(kout),
          (kprev >= 0) ? Tk(kprev) : nullptr, scale, cN1);
    };
    prop(0, 1, -1, 1.f, true);
    prop(1, 2, 0, 2.f, true);
    prop(2, 3, 1, 2.f, true);
    prop(3, 4, 2, 2.f, true);
    prop(4, 5, 3, 2.f, false);
    dim3 g((cN1 + 63) / 64, 1);
    gemm_mfma_kernel<1, 1><<<g, 256, 0, stream>>>(Th1, Wt1, b1, nullptr, out1h,
                                                  cN1, 128);
  }

  // pool1: out1h (fp16) -> Tlvl2 block 0
  csr_prop128h_kernel<<<(cN2 + 15) / 16, 256, 0, stream>>>(
      seg_off(4), seg_pairs(4), out1h, Tlvl2, Th2, nullptr, 1.f, cN2);

  // ================= Level 2 (no relu, N=256) =================
  {
    auto Tk  = [&](int k) { return Tlvl2 + (size_t)k * cN2 * 128; };
    auto Thk = [&](int k) { return Th2 + (size_t)k * cN2 * 128; };
    auto prop = [&](int kin, int kout, int kprev, float scale, bool needF32) {
      csr_prop128h_kernel<<<(cN2 + 15) / 16, 256, 0, stream>>>(
          seg_off(2), seg_pairs(2), Thk(kin), needF32 ? Tk(kout) : nullptr, Thk(kout),
          (kprev >= 0) ? Tk(kprev) : nullptr, scale, cN2);
    };
    prop(0, 1, -1, 1.f, true);
    prop(1, 2, 0, 2.f, true);
    prop(2, 3, 1, 2.f, true);
    prop(3, 4, 2, 2.f, true);
    prop(4, 5, 3, 2.f, false);
    dim3 g((cN2 + 63) / 64, 2);
    gemm_mfma_kernel<0, 0><<<g, 256, 0, stream>>>(Th2, Wt2, b2, out2, nullptr,
                                                  cN2, 256);
  }

  // ---- linear head (out pre-initialized with linb in prep) ----
  linear_kernel<<<512, 256, 0, stream>>>(linW, out2, out, cD);
}